// Round 1
// baseline (693.420 us; speedup 1.0000x reference)
//
#include <hip/hip_runtime.h>

// ---------------------------------------------------------------------------
// Smolgen pipeline on MI355X (gfx950), bf16 MFMA, fp32 intermediates.
//   K1 k_tok    : x (1024,64,1024) @ W_tc^T           -> flat (1024,2048)
//   K2 k_gc     : flat @ W_gc^T + b, RMSNorm          -> g    (1024,256)
//   K3 k_gemm256: g (1024,256)  @ W_heads-as-(4096,256)^T -> H (1024,4096)
//   K4 k_gemm256: H (16384,256) @ W_logit(4096,256)^T     -> out (16384,4096)
// All weights are (out,in) row-major so the GEMM-B operand in [n][k] LDS
// layout is a direct row copy (no transposes anywhere).
// MFMA 16x16x32 bf16 fragment mapping (m89/m91-verified):
//   lane l: col16 = l&15, quad = l>>4
//   A frag: A[m=col16][k = quad*8 + j]   (8 contiguous bf16 along K)
//   B frag: B[k = quad*8 + j][n=col16]   (8 contiguous along K of B^T row)
//   C/D   : col = col16, row = quad*4 + reg
// ---------------------------------------------------------------------------

typedef __attribute__((ext_vector_type(8))) short bf16x8;
typedef __attribute__((ext_vector_type(4))) float f32x4;

#define MFMA16(a, b, c) __builtin_amdgcn_mfma_f32_16x16x32_bf16((a), (b), (c), 0, 0, 0)

__device__ __forceinline__ unsigned short f2bf(float f) {
  // round-to-nearest-even fp32 -> bf16 (inputs are finite normals)
  union { float f; unsigned u; } v; v.f = f;
  unsigned r = v.u + 0x7fffu + ((v.u >> 16) & 1u);
  return (unsigned short)(r >> 16);
}

// Load 16 consecutive fp32 from global, convert, write 32 B (2x b128) to LDS.
__device__ __forceinline__ void stage16(const float* __restrict__ g,
                                        unsigned short* dst) {
  float4 f0 = ((const float4*)g)[0];
  float4 f1 = ((const float4*)g)[1];
  float4 f2 = ((const float4*)g)[2];
  float4 f3 = ((const float4*)g)[3];
  union { bf16x8 v; unsigned short s[8]; } u0, u1;
  u0.s[0] = f2bf(f0.x); u0.s[1] = f2bf(f0.y); u0.s[2] = f2bf(f0.z); u0.s[3] = f2bf(f0.w);
  u0.s[4] = f2bf(f1.x); u0.s[5] = f2bf(f1.y); u0.s[6] = f2bf(f1.z); u0.s[7] = f2bf(f1.w);
  u1.s[0] = f2bf(f2.x); u1.s[1] = f2bf(f2.y); u1.s[2] = f2bf(f2.z); u1.s[3] = f2bf(f2.w);
  u1.s[4] = f2bf(f3.x); u1.s[5] = f2bf(f3.y); u1.s[6] = f2bf(f3.z); u1.s[7] = f2bf(f3.w);
  *(bf16x8*)(dst)     = u0.v;
  *(bf16x8*)(dst + 8) = u1.v;
}

// --------------------------- K1: token compress ----------------------------
// One block per batch element b: C(64x32) = x[b](64x1024) @ W_tc^T(1024x32)
__global__ __launch_bounds__(256) void k_tok(const float* __restrict__ x,
                                             const float* __restrict__ Wtc,
                                             float* __restrict__ flat) {
  __shared__ unsigned short la[64][72];  // x chunk  [m][k], BK=64, pad 8
  __shared__ unsigned short lb[32][72];  // W_tc chunk [n][k]
  const int b = blockIdx.x;
  const int t = threadIdx.x;
  const int w = t >> 6, l = t & 63;
  const int col16 = l & 15, quad = l >> 4;
  const float* xb = x + (size_t)b * 64 * 1024;

  f32x4 acc[2];
  acc[0] = (f32x4){0.f, 0.f, 0.f, 0.f};
  acc[1] = (f32x4){0.f, 0.f, 0.f, 0.f};

  for (int kk = 0; kk < 1024; kk += 64) {
    __syncthreads();
    { // stage A: 64 rows x 64 cols fp32 -> bf16
      int r = t >> 2, c0 = (t & 3) * 16;
      stage16(xb + (size_t)r * 1024 + kk + c0, &la[r][c0]);
    }
    if (t < 128) { // stage B: 32 rows x 64 cols
      int r = t >> 2, c0 = (t & 3) * 16;
      stage16(Wtc + (size_t)r * 1024 + kk + c0, &lb[r][c0]);
    }
    __syncthreads();
#pragma unroll
    for (int k2 = 0; k2 < 64; k2 += 32) {
      bf16x8 af = *(const bf16x8*)&la[w * 16 + col16][k2 + quad * 8];
      bf16x8 b0 = *(const bf16x8*)&lb[col16][k2 + quad * 8];
      bf16x8 b1 = *(const bf16x8*)&lb[16 + col16][k2 + quad * 8];
      acc[0] = MFMA16(af, b0, acc[0]);
      acc[1] = MFMA16(af, b1, acc[1]);
    }
  }
  float* outb = flat + (size_t)b * 2048;
#pragma unroll
  for (int nt = 0; nt < 2; ++nt)
#pragma unroll
    for (int r = 0; r < 4; ++r) {
      int m = w * 16 + quad * 4 + r;                 // token s within the 64
      outb[m * 32 + nt * 16 + col16] = acc[nt][r];   // flat[b, s*32 + kout]
    }
}

// ------------------ K2: global compress + bias + RMSNorm -------------------
// One block per 16 batch rows: g(16x256) = flat(16x2048) @ W_gc^T, RMS fused.
__global__ __launch_bounds__(256) void k_gc(const float* __restrict__ flat,
                                            const float* __restrict__ Wgc,
                                            const float* __restrict__ bgc,
                                            const float* __restrict__ rscale,
                                            float* __restrict__ g) {
  __shared__ unsigned short la[16][40];   // A chunk [m][k], BK=32
  __shared__ unsigned short lb[256][40];  // W_gc chunk [n][k]
  __shared__ float lg[16][257];           // biased pre-norm row cache
  __shared__ float lred[16][16];
  __shared__ float linv[16];
  const int b0 = blockIdx.x * 16;
  const int t = threadIdx.x;
  const int w = t >> 6, l = t & 63;
  const int col16 = l & 15, quad = l >> 4;

  f32x4 acc[4];
#pragma unroll
  for (int j = 0; j < 4; ++j) acc[j] = (f32x4){0.f, 0.f, 0.f, 0.f};

  for (int kk = 0; kk < 2048; kk += 32) {
    __syncthreads();
    if (t < 128) { // A: 16 rows x 32 cols
      int r = t >> 3, c4 = (t & 7) * 4;
      float4 f = *(const float4*)(flat + (size_t)(b0 + r) * 2048 + kk + c4);
      ushort4 us;
      us.x = f2bf(f.x); us.y = f2bf(f.y); us.z = f2bf(f.z); us.w = f2bf(f.w);
      *(ushort4*)&la[r][c4] = us;
    }
#pragma unroll
    for (int i = 0; i < 8; ++i) { // B: 256 rows x 32 cols
      int r = (t >> 3) + i * 32, c4 = (t & 7) * 4;
      float4 f = *(const float4*)(Wgc + (size_t)r * 2048 + kk + c4);
      ushort4 us;
      us.x = f2bf(f.x); us.y = f2bf(f.y); us.z = f2bf(f.z); us.w = f2bf(f.w);
      *(ushort4*)&lb[r][c4] = us;
    }
    __syncthreads();
    bf16x8 af = *(const bf16x8*)&la[col16][quad * 8];
#pragma unroll
    for (int j = 0; j < 4; ++j) {
      bf16x8 bf = *(const bf16x8*)&lb[(w * 4 + j) * 16 + col16][quad * 8];
      acc[j] = MFMA16(af, bf, acc[j]);
    }
  }
  // epilogue: bias into LDS, then RMSNorm over the 256 cols of each row
#pragma unroll
  for (int j = 0; j < 4; ++j)
#pragma unroll
    for (int r = 0; r < 4; ++r) {
      int n = (w * 4 + j) * 16 + col16;
      lg[quad * 4 + r][n] = acc[j][r] + bgc[n];
    }
  __syncthreads();
  {
    int row = t >> 4, seg = t & 15;
    float s = 0.f;
#pragma unroll
    for (int j = 0; j < 16; ++j) { float v = lg[row][seg * 16 + j]; s += v * v; }
    lred[row][seg] = s;
  }
  __syncthreads();
  if (t < 16) {
    float s = 0.f;
#pragma unroll
    for (int j = 0; j < 16; ++j) s += lred[t][j];
    linv[t] = 1.0f / sqrtf(s * (1.0f / 256.0f) + 1e-6f);
  }
  __syncthreads();
  {
    int row = t >> 4, c0 = (t & 15) * 16;
    float iv = linv[row];
#pragma unroll
    for (int j = 0; j < 16; ++j) {
      int n = c0 + j;
      g[(size_t)(b0 + row) * 256 + n] = lg[row][n] * iv * rscale[n];
    }
  }
}

// ------------------- K3/K4: (M x 256) @ (256 x 4096) GEMM ------------------
// Bw is (4096 x 256) row-major = B^T rows; C is (M x 4096) fp32.
// 128x128 block tile, 2x2 waves of 64x64, BK=64.
__global__ __launch_bounds__(256) void k_gemm256(const float* __restrict__ A,
                                                 const float* __restrict__ Bw,
                                                 float* __restrict__ C) {
  __shared__ unsigned short la[128][72];
  __shared__ unsigned short lb[128][72];
  const int t = threadIdx.x;
  const int w = t >> 6, l = t & 63;
  const int col16 = l & 15, quad = l >> 4;
  const int wm = w >> 1, wn = w & 1;
  const size_t am0 = (size_t)blockIdx.y * 128;
  const size_t bn0 = (size_t)blockIdx.x * 128;

  f32x4 acc[4][4];
#pragma unroll
  for (int i = 0; i < 4; ++i)
#pragma unroll
    for (int j = 0; j < 4; ++j) acc[i][j] = (f32x4){0.f, 0.f, 0.f, 0.f};

  for (int kk = 0; kk < 256; kk += 64) {
    __syncthreads();
    { // each thread stages 32 A-floats and 32 B-floats (half a row of 64)
      int r = t >> 1, c0 = (t & 1) * 32;
      const float* ap = A + (am0 + r) * 256 + kk + c0;
      const float* bp = Bw + (bn0 + r) * 256 + kk + c0;
      stage16(ap, &la[r][c0]);
      stage16(ap + 16, &la[r][c0 + 16]);
      stage16(bp, &lb[r][c0]);
      stage16(bp + 16, &lb[r][c0 + 16]);
    }
    __syncthreads();
#pragma unroll
    for (int k2 = 0; k2 < 64; k2 += 32) {
      bf16x8 af[4], bf[4];
#pragma unroll
      for (int i = 0; i < 4; ++i)
        af[i] = *(const bf16x8*)&la[wm * 64 + i * 16 + col16][k2 + quad * 8];
#pragma unroll
      for (int j = 0; j < 4; ++j)
        bf[j] = *(const bf16x8*)&lb[wn * 64 + j * 16 + col16][k2 + quad * 8];
#pragma unroll
      for (int i = 0; i < 4; ++i)
#pragma unroll
        for (int j = 0; j < 4; ++j)
          acc[i][j] = MFMA16(af[i], bf[j], acc[i][j]);
    }
  }
#pragma unroll
  for (int i = 0; i < 4; ++i)
#pragma unroll
    for (int j = 0; j < 4; ++j)
#pragma unroll
      for (int r = 0; r < 4; ++r) {
        size_t row = am0 + wm * 64 + i * 16 + quad * 4 + r;
        size_t c = bn0 + wn * 64 + j * 16 + col16;
        C[row * 4096 + c] = acc[i][j][r];
      }
}

// ---------------------------------------------------------------------------
extern "C" void kernel_launch(void* const* d_in, const int* in_sizes, int n_in,
                              void* d_out, int out_size, void* d_ws, size_t ws_size,
                              hipStream_t stream) {
  const float* x    = (const float*)d_in[0];  // (1024, 64, 1024)
  const float* Wtc  = (const float*)d_in[1];  // (32, 1024)
  const float* Wgc  = (const float*)d_in[2];  // (256, 2048)
  const float* bgc  = (const float*)d_in[3];  // (256,)
  const float* rsc  = (const float*)d_in[4];  // (256,)
  const float* Wh   = (const float*)d_in[5];  // (16,256,256) == (4096,256)
  const float* Wl   = (const float*)d_in[6];  // (4096, 256)
  float* out = (float*)d_out;                 // (1024,16,64,64) == (16384,4096)

  float* flat = (float*)d_ws;                       // 1024*2048
  float* g    = flat + (size_t)1024 * 2048;         // 1024*256
  float* H    = g + (size_t)1024 * 256;             // 1024*4096 (== 16384x256)

  k_tok<<<1024, 256, 0, stream>>>(x, Wtc, flat);
  k_gc<<<64, 256, 0, stream>>>(flat, Wgc, bgc, rsc, g);
  k_gemm256<<<dim3(32, 8), 256, 0, stream>>>(g, Wh, H);
  k_gemm256<<<dim3(32, 128), 256, 0, stream>>>(H, Wl, out);
}

// Round 2
// 512.319 us; speedup vs baseline: 1.3535x; 1.3535x over previous
//
#include <hip/hip_runtime.h>

// ---------------------------------------------------------------------------
// Smolgen pipeline, round 2: bf16 operands end-to-end, global_load_lds GEMMs.
//   k_cvt   : Wtc/Wgc/Wh/Wl fp32 -> bf16 (once per call)
//   k_tok   : x (1024,64,1024) fp32 @ Wtc_bf^T -> flat_bf (1024,2048) bf16
//             (x streamed global->regs as MFMA A-frags; only W in LDS)
//   k_gc_part: split-K(4x512) flat_bf @ Wgc_bf^T -> Hpart fp32 partials
//   k_gc_red : reduce 4 partials + bias + RMSNorm -> g_bf (1024,256) bf16
//   k_gemm<OBF>: (Mx256)bf16 @ (4096x256)bf16^T, m97-style global_load_lds
//             staging with XOR chunk swizzle. K3 -> H_bf bf16, K4 -> out fp32.
// Precision note: identical rounding points to round-1 (operands were rounded
// to bf16 at each GEMM input anyway); expected absmax ~0.031.
// MFMA 16x16x32 bf16 mapping: lane l: col16=l&15, quad=l>>4;
//   A[m=col16][k=quad*8+j], B[k=quad*8+j][n=col16], C: col=col16, row=quad*4+r.
// ---------------------------------------------------------------------------

typedef unsigned short ushort_t;
typedef __attribute__((ext_vector_type(8))) short bf16x8;
typedef __attribute__((ext_vector_type(4))) float f32x4;
typedef __attribute__((ext_vector_type(4))) unsigned int u32x4;

#define MFMA16(a, b, c) __builtin_amdgcn_mfma_f32_16x16x32_bf16((a), (b), (c), 0, 0, 0)

__device__ __forceinline__ unsigned bfround(float f) {
  unsigned u = __builtin_bit_cast(unsigned, f);
  return u + 0x7fffu + ((u >> 16) & 1u);   // RNE to bf16 in the high 16 bits
}
__device__ __forceinline__ unsigned pack2(float lo, float hi) {
  return (bfround(lo) >> 16) | (bfround(hi) & 0xffff0000u);
}
__device__ __forceinline__ ushort_t bf1(float f) { return (ushort_t)(bfround(f) >> 16); }

// async global->LDS, 16B per lane; lds dst = wave-uniform base + lane*16
__device__ __forceinline__ void gld16(const ushort_t* g, ushort_t* l) {
  __builtin_amdgcn_global_load_lds(
      (const __attribute__((address_space(1))) unsigned int*)g,
      (__attribute__((address_space(3))) unsigned int*)l, 16, 0, 0);
}

// ------------------------- weight conversion (once) ------------------------
__global__ __launch_bounds__(256) void k_cvt(const float* __restrict__ Wtc,
                                             const float* __restrict__ Wgc,
                                             const float* __restrict__ Wh,
                                             const float* __restrict__ Wl,
                                             ushort_t* __restrict__ oTc,
                                             ushort_t* __restrict__ oGc,
                                             ushort_t* __restrict__ oWh,
                                             ushort_t* __restrict__ oWl) {
  size_t g = (size_t)blockIdx.x * 256 + threadIdx.x;  // group of 8 elements
  const float* src; ushort_t* dst; size_t off;
  if (g < 4096)        { src = Wtc; dst = oTc; off = g; }
  else if (g < 69632)  { src = Wgc; dst = oGc; off = g - 4096; }
  else if (g < 200704) { src = Wh;  dst = oWh; off = g - 69632; }
  else                 { src = Wl;  dst = oWl; off = g - 200704; }
  float4 f0 = ((const float4*)src)[off * 2];
  float4 f1 = ((const float4*)src)[off * 2 + 1];
  u32x4 p;
  p.x = pack2(f0.x, f0.y); p.y = pack2(f0.z, f0.w);
  p.z = pack2(f1.x, f1.y); p.w = pack2(f1.z, f1.w);
  ((u32x4*)dst)[off] = p;
}

// --------------------------- K1: token compress ----------------------------
// One block per batch b; x streamed global->regs (lane loads its own A frag),
// Wtc_bf staged in LDS per 256-K chunk. C(64x32) -> flat_bf.
__global__ __launch_bounds__(256) void k_tok(const float* __restrict__ x,
                                             const ushort_t* __restrict__ WtcBf,
                                             ushort_t* __restrict__ flatBf) {
  __shared__ ushort_t lb[32][264];  // 32 rows x 256 K-chunk (+8 pad)
  const int t = threadIdx.x;
  const int w = t >> 6, l = t & 63, col16 = l & 15, quad = l >> 4;
  const float* arow = x + (size_t)blockIdx.x * 65536 + (size_t)(w * 16 + col16) * 1024;
  f32x4 acc0 = {0.f, 0.f, 0.f, 0.f}, acc1 = {0.f, 0.f, 0.f, 0.f};

  for (int ko = 0; ko < 1024; ko += 256) {
    // A loads for this chunk first (independent of LDS) — latency overlaps staging
    float4 af[16];
#pragma unroll
    for (int s = 0; s < 8; ++s) {
      af[2 * s]     = *(const float4*)(arow + ko + s * 32 + quad * 8);
      af[2 * s + 1] = *(const float4*)(arow + ko + s * 32 + quad * 8 + 4);
    }
    __syncthreads();
    {  // stage W chunk: 32 rows x 256 bf16, 64 B per thread
      int r = t >> 3, c0 = (t & 7) * 32;
      const ushort_t* src = WtcBf + (size_t)r * 1024 + ko + c0;
#pragma unroll
      for (int c = 0; c < 4; ++c)
        *(bf16x8*)&lb[r][c0 + c * 8] = *(const bf16x8*)(src + c * 8);
    }
    __syncthreads();
#pragma unroll
    for (int s = 0; s < 8; ++s) {
      u32x4 p;
      p.x = pack2(af[2 * s].x, af[2 * s].y);
      p.y = pack2(af[2 * s].z, af[2 * s].w);
      p.z = pack2(af[2 * s + 1].x, af[2 * s + 1].y);
      p.w = pack2(af[2 * s + 1].z, af[2 * s + 1].w);
      bf16x8 a = __builtin_bit_cast(bf16x8, p);
      bf16x8 b0 = *(const bf16x8*)&lb[col16][s * 32 + quad * 8];
      bf16x8 b1 = *(const bf16x8*)&lb[16 + col16][s * 32 + quad * 8];
      acc0 = MFMA16(a, b0, acc0);
      acc1 = MFMA16(a, b1, acc1);
    }
  }
  ushort_t* ob = flatBf + (size_t)blockIdx.x * 2048;
#pragma unroll
  for (int r = 0; r < 4; ++r) {
    int m = w * 16 + quad * 4 + r;
    ob[m * 32 + col16]      = bf1(acc0[r]);
    ob[m * 32 + 16 + col16] = bf1(acc1[r]);
  }
}

// ------------------ K2a: global compress, split-K partials -----------------
// grid (64 m-blocks, 4 k-slices of 512). BM=16, N=256, BK=32.
__global__ __launch_bounds__(256) void k_gc_part(const ushort_t* __restrict__ Abf,
                                                 const ushort_t* __restrict__ Bbf,
                                                 float* __restrict__ Hpart) {
  __shared__ ushort_t la[16][40];
  __shared__ ushort_t lb[256][40];
  const int t = threadIdx.x;
  const int w = t >> 6, l = t & 63, col16 = l & 15, quad = l >> 4;
  const int b0 = blockIdx.x * 16;
  const int k0 = blockIdx.y * 512;
  f32x4 acc[4];
#pragma unroll
  for (int j = 0; j < 4; ++j) acc[j] = (f32x4){0.f, 0.f, 0.f, 0.f};

  for (int kk = 0; kk < 512; kk += 32) {
    __syncthreads();
    if (t < 128) {  // A: 16 rows x 32 bf16
      int r = t >> 3, c0 = (t & 7) * 4;
      *(ushort4*)&la[r][c0] =
          *(const ushort4*)(Abf + (size_t)(b0 + r) * 2048 + k0 + kk + c0);
    }
    {  // B: 256 rows x 32 bf16, one row per thread
      const ushort_t* src = Bbf + (size_t)t * 2048 + k0 + kk;
#pragma unroll
      for (int c = 0; c < 4; ++c)
        *(bf16x8*)&lb[t][c * 8] = *(const bf16x8*)(src + c * 8);
    }
    __syncthreads();
    bf16x8 af = *(const bf16x8*)&la[col16][quad * 8];
#pragma unroll
    for (int j = 0; j < 4; ++j) {
      bf16x8 bf = *(const bf16x8*)&lb[w * 64 + j * 16 + col16][quad * 8];
      acc[j] = MFMA16(af, bf, acc[j]);
    }
  }
  float* o = Hpart + (size_t)blockIdx.y * 262144;  // 1024*256 per slice
#pragma unroll
  for (int j = 0; j < 4; ++j)
#pragma unroll
    for (int r = 0; r < 4; ++r)
      o[(size_t)(b0 + quad * 4 + r) * 256 + w * 64 + j * 16 + col16] = acc[j][r];
}

// ---------------- K2b: reduce partials + bias + RMSNorm -> bf16 ------------
__global__ __launch_bounds__(256) void k_gc_red(const float* __restrict__ Hpart,
                                                const float* __restrict__ bias,
                                                const float* __restrict__ rscale,
                                                ushort_t* __restrict__ gBf) {
  __shared__ float lred[16][17];
  __shared__ float linv[16];
  const int t = threadIdx.x;
  const int row = t >> 4, seg = t & 15;
  const size_t base = (size_t)(blockIdx.x * 16 + row) * 256 + seg * 16;
  float v[16];
#pragma unroll
  for (int k = 0; k < 4; ++k) {
    float4 s0 = *(const float4*)(Hpart + base + k * 4);
    float4 s1 = *(const float4*)(Hpart + 262144 + base + k * 4);
    float4 s2 = *(const float4*)(Hpart + 524288 + base + k * 4);
    float4 s3 = *(const float4*)(Hpart + 786432 + base + k * 4);
    float4 bi = *(const float4*)(bias + seg * 16 + k * 4);
    v[k * 4 + 0] = s0.x + s1.x + s2.x + s3.x + bi.x;
    v[k * 4 + 1] = s0.y + s1.y + s2.y + s3.y + bi.y;
    v[k * 4 + 2] = s0.z + s1.z + s2.z + s3.z + bi.z;
    v[k * 4 + 3] = s0.w + s1.w + s2.w + s3.w + bi.w;
  }
  float ss = 0.f;
#pragma unroll
  for (int k = 0; k < 16; ++k) ss += v[k] * v[k];
  lred[row][seg] = ss;
  __syncthreads();
  if (t < 16) {
    float s = 0.f;
#pragma unroll
    for (int k = 0; k < 16; ++k) s += lred[t][k];
    linv[t] = 1.0f / sqrtf(s * (1.0f / 256.0f) + 1e-6f);
  }
  __syncthreads();
  float iv = linv[row];
  float rs[16];
#pragma unroll
  for (int k = 0; k < 4; ++k)
    *(float4*)&rs[k * 4] = *(const float4*)(rscale + seg * 16 + k * 4);
  u32x4 p0, p1;
  p0.x = pack2(v[0] * iv * rs[0],  v[1] * iv * rs[1]);
  p0.y = pack2(v[2] * iv * rs[2],  v[3] * iv * rs[3]);
  p0.z = pack2(v[4] * iv * rs[4],  v[5] * iv * rs[5]);
  p0.w = pack2(v[6] * iv * rs[6],  v[7] * iv * rs[7]);
  p1.x = pack2(v[8] * iv * rs[8],  v[9] * iv * rs[9]);
  p1.y = pack2(v[10] * iv * rs[10], v[11] * iv * rs[11]);
  p1.z = pack2(v[12] * iv * rs[12], v[13] * iv * rs[13]);
  p1.w = pack2(v[14] * iv * rs[14], v[15] * iv * rs[15]);
  *(u32x4*)(gBf + base) = p0;
  *(u32x4*)(gBf + base + 8) = p1;
}

// -------- K3/K4: (Mx256)bf16 @ (4096x256)bf16^T, global_load_lds staging ---
// 128x128 tile, 2x2 waves of 64x64, BK=64, XOR chunk swizzle (chunk=16B=8bf16):
//   LDS[r][c] holds global chunk c^(r&7) of row r  -> ds_read_b128 at bank floor.
template <bool OBF>
__global__ __launch_bounds__(256) void k_gemm(const ushort_t* __restrict__ A,
                                              const ushort_t* __restrict__ Bw,
                                              float* __restrict__ Cf,
                                              ushort_t* __restrict__ Cb) {
  __shared__ ushort_t la[128 * 64];
  __shared__ ushort_t lb[128 * 64];
  const int t = threadIdx.x;
  const int w = t >> 6, l = t & 63, col16 = l & 15, quad = l >> 4;
  const int wm = w >> 1, wn = w & 1;
  const size_t am0 = (size_t)blockIdx.y * 128;
  const size_t bn0 = (size_t)blockIdx.x * 128;

  f32x4 acc[4][4];
#pragma unroll
  for (int i = 0; i < 4; ++i)
#pragma unroll
    for (int j = 0; j < 4; ++j) acc[i][j] = (f32x4){0.f, 0.f, 0.f, 0.f};

  for (int kk = 0; kk < 256; kk += 64) {
    __syncthreads();
#pragma unroll
    for (int i = 0; i < 4; ++i) {
      int L = i * 256 + t;                 // chunk index 0..1023
      int r = L >> 3;
      int cs = (L & 7) ^ (r & 7);          // swizzled global chunk
      ushort_t* ldst_a = la + (size_t)((i * 256 + (w << 6)) << 3);  // wave base
      ushort_t* ldst_b = lb + (size_t)((i * 256 + (w << 6)) << 3);
      gld16(A + (am0 + r) * 256 + kk + cs * 8, ldst_a);
      gld16(Bw + (bn0 + r) * 256 + kk + cs * 8, ldst_b);
    }
    __syncthreads();
#pragma unroll
    for (int k2 = 0; k2 < 64; k2 += 32) {
      const int cg = (k2 >> 3) + quad;     // global chunk within row
      bf16x8 af[4], bf[4];
#pragma unroll
      for (int i = 0; i < 4; ++i) {
        int R = wm * 64 + i * 16 + col16;
        af[i] = *(const bf16x8*)(la + (size_t)((R * 8 + (cg ^ (R & 7))) << 3));
      }
#pragma unroll
      for (int j = 0; j < 4; ++j) {
        int R = wn * 64 + j * 16 + col16;
        bf[j] = *(const bf16x8*)(lb + (size_t)((R * 8 + (cg ^ (R & 7))) << 3));
      }
#pragma unroll
      for (int i = 0; i < 4; ++i)
#pragma unroll
        for (int j = 0; j < 4; ++j)
          acc[i][j] = MFMA16(af[i], bf[j], acc[i][j]);
    }
  }
#pragma unroll
  for (int i = 0; i < 4; ++i)
#pragma unroll
    for (int j = 0; j < 4; ++j)
#pragma unroll
      for (int r = 0; r < 4; ++r) {
        size_t row = am0 + wm * 64 + i * 16 + quad * 4 + r;
        size_t c = bn0 + wn * 64 + j * 16 + col16;
        if (OBF) Cb[row * 4096 + c] = bf1(acc[i][j][r]);
        else     Cf[row * 4096 + c] = acc[i][j][r];
      }
}

// ---------------------------------------------------------------------------
extern "C" void kernel_launch(void* const* d_in, const int* in_sizes, int n_in,
                              void* d_out, int out_size, void* d_ws, size_t ws_size,
                              hipStream_t stream) {
  const float* x   = (const float*)d_in[0];  // (1024,64,1024)
  const float* Wtc = (const float*)d_in[1];  // (32,1024)
  const float* Wgc = (const float*)d_in[2];  // (256,2048)
  const float* bgc = (const float*)d_in[3];  // (256,)
  const float* rsc = (const float*)d_in[4];  // (256,)
  const float* Wh  = (const float*)d_in[5];  // (16,256,256)=(4096,256)
  const float* Wl  = (const float*)d_in[6];  // (4096,256)
  float* out = (float*)d_out;                // (16384,4096) fp32

  char* ws = (char*)d_ws;                    // all offsets 256B-aligned
  ushort_t* oTc    = (ushort_t*)(ws);                    //   64 KB
  ushort_t* oGc    = (ushort_t*)(ws + 65536);            //    1 MB
  ushort_t* oWh    = (ushort_t*)(ws + 1114112);          //    2 MB
  ushort_t* oWl    = (ushort_t*)(ws + 3211264);          //    2 MB
  ushort_t* flatBf = (ushort_t*)(ws + 5308416);          //    4 MB
  ushort_t* gBf    = (ushort_t*)(ws + 9502720);          //  512 KB
  ushort_t* HBf    = (ushort_t*)(ws + 10027008);         //    8 MB
  float*    Hpart  = (float*)(ws + 18415616);            //    4 MB

  k_cvt<<<1296, 256, 0, stream>>>(Wtc, Wgc, Wh, Wl, oTc, oGc, oWh, oWl);
  k_tok<<<1024, 256, 0, stream>>>(x, oTc, flatBf);
  k_gc_part<<<dim3(64, 4), 256, 0, stream>>>(flatBf, oGc, Hpart);
  k_gc_red<<<64, 256, 0, stream>>>(Hpart, bgc, rsc, gBf);
  k_gemm<true><<<dim3(32, 8), 256, 0, stream>>>(gBf, oWh, nullptr, HBf);
  k_gemm<false><<<dim3(32, 128), 256, 0, stream>>>(HBf, oWl, out, nullptr);
}